// Round 8
// baseline (91.562 us; speedup 1.0000x reference)
//
#include <hip/hip_runtime.h>

#define B_TOT   8192
#define F_DIM   256
#define T_TREES 32
#define N_NODES 63
#define P_DIM   8
#define BM      128
#define SHRINK  0.1f

typedef __bf16 bf16_t;
typedef bf16_t bf16x8 __attribute__((ext_vector_type(8)));
typedef float  f32x4  __attribute__((ext_vector_type(4)));
typedef unsigned short ushort8_t __attribute__((ext_vector_type(8)));
typedef unsigned short ushort4_t __attribute__((ext_vector_type(4)));

__device__ __forceinline__ unsigned short f2bf(float f) {
    unsigned int u = __float_as_uint(f);
    u += 0x7fffu + ((u >> 16) & 1u);
    return (unsigned short)(u >> 16);
}
__device__ __forceinline__ unsigned int pk2bf(float a, float b) {
    unsigned int ua = __float_as_uint(a); ua += 0x7fffu + ((ua >> 16) & 1u);
    unsigned int ub = __float_as_uint(b); ub += 0x7fffu + ((ub >> 16) & 1u);
    return (ua >> 16) | (ub & 0xffff0000u);
}
__device__ __forceinline__ void gl_lds16(const void* g, void* l) {
    __builtin_amdgcn_global_load_lds(
        (const __attribute__((address_space(1))) unsigned int*)g,
        (__attribute__((address_space(3))) unsigned int*)l, 16, 0, 0);
}

// ---------- fused convert + out-zero kernel ----------
__global__ __launch_bounds__(256) void cvt_all(
    const float* __restrict__ x, const float* __restrict__ W,
    const float* __restrict__ phi,
    unsigned short* __restrict__ xb, unsigned short* __restrict__ Wb,
    unsigned short* __restrict__ phiB, float* __restrict__ out)
{
    const int bx  = blockIdx.x;
    const int tid = threadIdx.x;
    if (bx < 2048) {                       // x: 524288 float4
        const int i = bx * 256 + tid;
        const float4 v = *(const float4*)&x[(size_t)i * 4];
        ushort4_t h;
        h.x = f2bf(v.x); h.y = f2bf(v.y); h.z = f2bf(v.z); h.w = f2bf(v.w);
        *(ushort4_t*)&xb[(size_t)i * 4] = h;
    } else if (bx < 2560) {                // W: pad 63->64 rows/tree
        const int i = (bx - 2048) * 256 + tid;
        const int tree = i >> 12;
        const int rem  = i & 4095;
        const int row  = rem >> 6;
        const int c4   = rem & 63;
        float4 v = make_float4(0.f, 0.f, 0.f, 0.f);
        if (row < N_NODES)
            v = *(const float4*)&W[((size_t)(tree * N_NODES + row)) * F_DIM + c4 * 4];
        ushort4_t h;
        h.x = f2bf(v.x); h.y = f2bf(v.y); h.z = f2bf(v.z); h.w = f2bf(v.w);
        *(ushort4_t*)&Wb[(size_t)i * 4] = h;
    } else if (bx < 2576) {                // phi B-frags: lane l holds B[k=quad*8+j][n=l&15]
        const int i = (bx - 2560) * 256 + tid;   // 0..4095
        const int tree = i >> 7;
        const int rem  = i & 127;
        const int k2   = rem >> 6;
        const int lane = rem & 63;
        const int lm   = lane & 15;
        const int quad = lane >> 4;
        ushort8_t h;
#pragma unroll
        for (int j = 0; j < 8; ++j) {
            float v = 0.f;
            if (lm < 8) v = phi[(size_t)tree * 512 + (k2 * 32 + quad * 8 + j) * 8 + lm];
            h[j] = f2bf(v);
        }
        *(ushort8_t*)&phiB[(size_t)i * 8] = h;
    } else {                               // zero out: 16384 float4
        const int i = (bx - 2576) * 256 + tid;
        *(float4*)&out[(size_t)i * 4] = make_float4(0.f, 0.f, 0.f, 0.f);
    }
}

// ---------- main: GEMM + sigmoid + wave-local walk/phi (1 epilogue barrier total) ----------
__global__ __launch_bounds__(256, 4) void softgbm_main(
    const unsigned short* __restrict__ xb, const unsigned short* __restrict__ Wb,
    const unsigned short* __restrict__ phiB, const float* __restrict__ bias,
    float* __restrict__ out)
{
    __shared__ union Smem {
        struct { unsigned short A[BM * 64]; unsigned short B[BM * 64]; } g;  // 32 KB
        unsigned short ss[2 * BM * 64];   // [tree][row][64], chunk-swizzled  // 32 KB
    } sm;
    __shared__ float bs2[2][64];

    const int tid  = threadIdx.x;
    const int tp   = blockIdx.x;            // tree pair 0..15
    const int b0   = blockIdx.y * BM;
    const int wave = tid >> 6;
    const int lane = tid & 63;
    const int quad = lane >> 4;
    const int lm   = lane & 15;
    const int wr   = wave >> 1;             // row half (64 rows)
    const int wc   = wave & 1;              // tree whose cols this wave computes

    if (tid < 128) {
        const int p = tid >> 6, node = tid & 63;
        bs2[p][node] = (node < N_NODES) ? bias[(tp * 2 + p) * N_NODES + node] : 0.f;
    }

    // phi B-frags for this wave's tree (wc), prefetched before GEMM
    bf16x8 pb[2];
#pragma unroll
    for (int k2 = 0; k2 < 2; ++k2)
        pb[k2] = __builtin_bit_cast(bf16x8,
            *(const ushort8_t*)&phiB[(size_t)(((tp * 2 + wc) * 2 + k2) * 64 + lane) * 8]);

    f32x4 acc[4][4];
#pragma unroll
    for (int m = 0; m < 4; ++m)
#pragma unroll
        for (int n = 0; n < 4; ++n)
            acc[m][n] = f32x4{0.f, 0.f, 0.f, 0.f};

    // ---- GEMM: C[128 x (2 trees x 64 nodes)] = xb . Wb^T, K=256, BK=64 ----
    for (int ko = 0; ko < F_DIM; ko += 64) {
        __syncthreads();
#pragma unroll
        for (int i = 0; i < 4; ++i) {
            const int r = wave * 32 + i * 8 + (lane >> 3);
            const int c = (lane & 7) ^ (r & 7);
            gl_lds16(&xb[(size_t)(b0 + r) * F_DIM + ko + c * 8],
                     &sm.g.A[(wave * 32 + i * 8) * 64]);
        }
#pragma unroll
        for (int i = 0; i < 4; ++i) {
            const int r = wave * 32 + i * 8 + (lane >> 3);
            const int c = (lane & 7) ^ (r & 7);
            gl_lds16(&Wb[(size_t)(tp * 128 + r) * F_DIM + ko + c * 8],
                     &sm.g.B[(wave * 32 + i * 8) * 64]);
        }
        __syncthreads();

#pragma unroll
        for (int ks = 0; ks < 2; ++ks) {
            bf16x8 af[4], bfr[4];
#pragma unroll
            for (int m = 0; m < 4; ++m) {
                const int r  = wr * 64 + m * 16 + lm;
                const int cp = (ks * 4 + quad) ^ (r & 7);
                af[m] = __builtin_bit_cast(bf16x8, *(ushort8_t*)&sm.g.A[r * 64 + cp * 8]);
            }
#pragma unroll
            for (int n = 0; n < 4; ++n) {
                const int r  = wc * 64 + n * 16 + lm;
                const int cp = (ks * 4 + quad) ^ (r & 7);
                bfr[n] = __builtin_bit_cast(bf16x8, *(ushort8_t*)&sm.g.B[r * 64 + cp * 8]);
            }
#pragma unroll
            for (int m = 0; m < 4; ++m)
#pragma unroll
                for (int n = 0; n < 4; ++n)
                    acc[m][n] = __builtin_amdgcn_mfma_f32_16x16x32_bf16(af[m], bfr[n], acc[m][n], 0, 0, 0);
        }
    }
    __syncthreads();   // GEMM LDS reads done; union becomes ss space

    // ---- sigmoid -> ss[wc][row][node], natural node order, chunk-swizzled; acc dies ----
#pragma unroll
    for (int m = 0; m < 4; ++m)
#pragma unroll
        for (int n = 0; n < 4; ++n) {
            const int node = n * 16 + lm;
            const float bb = bs2[wc][node];
#pragma unroll
            for (int reg = 0; reg < 4; ++reg) {
                const int rr = wr * 64 + m * 16 + quad * 4 + reg;
                const float z = acc[m][n][reg] + bb;
                const unsigned short sv = f2bf(__frcp_rn(1.0f + __expf(-z)));
                if (node < N_NODES)
                    sm.ss[(wc * BM + rr) * 64 + ((node >> 3) ^ (rr & 7)) * 8 + (node & 7)] = sv;
            }
        }
    __syncthreads();   // the ONLY epilogue barrier (ss rows cross wave GEMM/sigmoid regions)

    // ---- wave-local single-pass epilogue: tree=wave&1, rows=(wave>>1)*64+lane ----
    // (identical to the sigmoid writer mapping -> no further barriers needed)
    const int row = wr * 64 + lane;         // this thread's row
    const int rs  = row & 7;
    unsigned short* srow = &sm.ss[(wc * BM + row) * 64];

    // full row (63 nodes) into registers: 8x b128, unswizzle via c^rs
    unsigned int w[32];
#pragma unroll
    for (int c = 0; c < 8; ++c)
        *(uint4*)&w[c * 4] = *(const uint4*)&srow[(c ^ rs) * 8];

#define VAL(j) ((j) & 1 ? __uint_as_float(w[(j) >> 1] & 0xffff0000u) \
                        : __uint_as_float(w[(j) >> 1] << 16))
    float q1[2], q2[4], q3[8], q4[16], q5[32];
    {
        const float s0 = VAL(0);
        q1[1] = s0; q1[0] = 1.0f - s0;
    }
#pragma unroll
    for (int v = 0; v < 2; ++v) {
        const float tv = VAL(1 + v);
        q2[2 * v + 1] = q1[v] * tv; q2[2 * v] = q1[v] - q2[2 * v + 1];
    }
#pragma unroll
    for (int v = 0; v < 4; ++v) {
        const float tv = VAL(3 + v);
        q3[2 * v + 1] = q2[v] * tv; q3[2 * v] = q2[v] - q3[2 * v + 1];
    }
#pragma unroll
    for (int v = 0; v < 8; ++v) {
        const float tv = VAL(7 + v);
        q4[2 * v + 1] = q3[v] * tv; q4[2 * v] = q3[v] - q4[2 * v + 1];
    }
#pragma unroll
    for (int v = 0; v < 16; ++v) {
        const float tv = VAL(15 + v);
        q5[2 * v + 1] = q4[v] * tv; q5[2 * v] = q4[v] - q5[2 * v + 1];
    }
    // leaves (8 chunks of 8) overlay in-place on this thread's own ss row
#pragma unroll
    for (int i = 0; i < 8; ++i) {
        float q6[8];
#pragma unroll
        for (int v = 0; v < 4; ++v) {
            const float tv = VAL(31 + i * 4 + v);
            q6[2 * v + 1] = q5[i * 4 + v] * tv;
            q6[2 * v]     = q5[i * 4 + v] - q6[2 * v + 1];
        }
        uint4 wv;
        wv.x = pk2bf(q6[0], q6[1]);
        wv.y = pk2bf(q6[2], q6[3]);
        wv.z = pk2bf(q6[4], q6[5]);
        wv.w = pk2bf(q6[6], q6[7]);
        *(uint4*)&srow[(i ^ rs) * 8] = wv;
    }
#undef VAL

    // ---- phi contraction: wave-local MFMA over this wave's 64 rows, K=64 leaves ----
    f32x4 accp[4];
#pragma unroll
    for (int mg = 0; mg < 4; ++mg) accp[mg] = f32x4{0.f, 0.f, 0.f, 0.f};
#pragma unroll
    for (int mg = 0; mg < 4; ++mg)
#pragma unroll
        for (int k2 = 0; k2 < 2; ++k2) {
            const int r2 = wr * 64 + mg * 16 + lm;
            const int cp = (k2 * 4 + quad) ^ (r2 & 7);
            const bf16x8 afr = __builtin_bit_cast(bf16x8,
                *(ushort8_t*)&sm.ss[(wc * BM + r2) * 64 + cp * 8]);
            accp[mg] = __builtin_amdgcn_mfma_f32_16x16x32_bf16(afr, pb[k2], accp[mg], 0, 0, 0);
        }

    // ---- commit: col=lm (0..7), row=quad*4+reg ----
    if (lm < P_DIM) {
#pragma unroll
        for (int mg = 0; mg < 4; ++mg)
#pragma unroll
            for (int reg = 0; reg < 4; ++reg) {
                const int r2 = wr * 64 + mg * 16 + quad * 4 + reg;
                atomicAdd(&out[(size_t)(b0 + r2) * P_DIM + lm], SHRINK * accp[mg][reg]);
            }
    }
}

extern "C" void kernel_launch(void* const* d_in, const int* in_sizes, int n_in,
                              void* d_out, int out_size, void* d_ws, size_t ws_size,
                              hipStream_t stream) {
    const float* x    = (const float*)d_in[0];
    const float* W    = (const float*)d_in[1];
    const float* bias = (const float*)d_in[2];
    const float* phi  = (const float*)d_in[3];
    float* out = (float*)d_out;

    unsigned short* xb   = (unsigned short*)d_ws;                    // 4 MB
    unsigned short* Wb   = xb + (size_t)B_TOT * F_DIM;               // 1 MB
    unsigned short* phiB = Wb + (size_t)T_TREES * 64 * F_DIM;        // 64 KB

    cvt_all<<<dim3(2640), dim3(256), 0, stream>>>(x, W, phi, xb, Wb, phiB, out);

    dim3 grid(T_TREES / 2, B_TOT / BM);
    softgbm_main<<<grid, dim3(256), 0, stream>>>(xb, Wb, phiB, bias, out);
}

// Round 9
// 82.603 us; speedup vs baseline: 1.1085x; 1.1085x over previous
//
#include <hip/hip_runtime.h>

#define B_TOT   8192
#define F_DIM   256
#define T_TREES 32
#define N_NODES 63
#define P_DIM   8
#define BM      128
#define SHRINK  0.1f

typedef __bf16 bf16_t;
typedef bf16_t bf16x8 __attribute__((ext_vector_type(8)));
typedef bf16_t bf16x2 __attribute__((ext_vector_type(2)));
typedef float  f32x4  __attribute__((ext_vector_type(4)));
typedef float  f32x2  __attribute__((ext_vector_type(2)));
typedef unsigned short ushort8_t __attribute__((ext_vector_type(8)));
typedef unsigned short ushort4_t __attribute__((ext_vector_type(4)));

// manual RNE (used only in memory-bound cvt kernel)
__device__ __forceinline__ unsigned short f2bf(float f) {
    unsigned int u = __float_as_uint(f);
    u += 0x7fffu + ((u >> 16) & 1u);
    return (unsigned short)(u >> 16);
}
// hardware bf16 converts (RNE on gfx950)
__device__ __forceinline__ unsigned short f2bf_hw(float f) {
    const __bf16 b = (__bf16)f;
    return __builtin_bit_cast(unsigned short, b);
}
__device__ __forceinline__ unsigned int pk2bf_hw(float a, float b) {
    f32x2 v; v.x = a; v.y = b;
    const bf16x2 r = __builtin_convertvector(v, bf16x2);
    return __builtin_bit_cast(unsigned int, r);
}
__device__ __forceinline__ float fast_rcp(float x) {
#if __has_builtin(__builtin_amdgcn_rcpf)
    return __builtin_amdgcn_rcpf(x);
#else
    return 1.0f / x;
#endif
}
__device__ __forceinline__ void gl_lds16(const void* g, void* l) {
    __builtin_amdgcn_global_load_lds(
        (const __attribute__((address_space(1))) unsigned int*)g,
        (__attribute__((address_space(3))) unsigned int*)l, 16, 0, 0);
}

// ---------- fused convert + out-zero kernel ----------
__global__ __launch_bounds__(256) void cvt_all(
    const float* __restrict__ x, const float* __restrict__ W,
    const float* __restrict__ phi,
    unsigned short* __restrict__ xb, unsigned short* __restrict__ Wb,
    unsigned short* __restrict__ phiB, float* __restrict__ out)
{
    const int bx  = blockIdx.x;
    const int tid = threadIdx.x;
    if (bx < 2048) {                       // x: 524288 float4
        const int i = bx * 256 + tid;
        const float4 v = *(const float4*)&x[(size_t)i * 4];
        ushort4_t h;
        h.x = f2bf(v.x); h.y = f2bf(v.y); h.z = f2bf(v.z); h.w = f2bf(v.w);
        *(ushort4_t*)&xb[(size_t)i * 4] = h;
    } else if (bx < 2560) {                // W: pad 63->64 rows/tree
        const int i = (bx - 2048) * 256 + tid;
        const int tree = i >> 12;
        const int rem  = i & 4095;
        const int row  = rem >> 6;
        const int c4   = rem & 63;
        float4 v = make_float4(0.f, 0.f, 0.f, 0.f);
        if (row < N_NODES)
            v = *(const float4*)&W[((size_t)(tree * N_NODES + row)) * F_DIM + c4 * 4];
        ushort4_t h;
        h.x = f2bf(v.x); h.y = f2bf(v.y); h.z = f2bf(v.z); h.w = f2bf(v.w);
        *(ushort4_t*)&Wb[(size_t)i * 4] = h;
    } else if (bx < 2576) {                // phi B-frags: lane l holds B[k=quad*8+j][n=l&15]
        const int i = (bx - 2560) * 256 + tid;   // 0..4095
        const int tree = i >> 7;
        const int rem  = i & 127;
        const int k2   = rem >> 6;
        const int lane = rem & 63;
        const int lm   = lane & 15;
        const int quad = lane >> 4;
        ushort8_t h;
#pragma unroll
        for (int j = 0; j < 8; ++j) {
            float v = 0.f;
            if (lm < 8) v = phi[(size_t)tree * 512 + (k2 * 32 + quad * 8 + j) * 8 + lm];
            h[j] = f2bf(v);
        }
        *(ushort8_t*)&phiB[(size_t)i * 8] = h;
    } else {                               // zero out: 16384 float4
        const int i = (bx - 2576) * 256 + tid;
        *(float4*)&out[(size_t)i * 4] = make_float4(0.f, 0.f, 0.f, 0.f);
    }
}

// ---------- main fused kernel: GEMM + sigmoid-scatter + walk + phi ----------
__global__ __launch_bounds__(256, 4) void softgbm_main(
    const unsigned short* __restrict__ xb, const unsigned short* __restrict__ Wb,
    const unsigned short* __restrict__ phiB, const float* __restrict__ bias,
    float* __restrict__ out)
{
    __shared__ union Smem {
        struct { unsigned short A[BM * 64]; unsigned short B[BM * 64]; } g;  // 32 KB
        unsigned short ss[2 * BM * 64];                                      // 32 KB
    } sm;
    __shared__ float bs2[2][64];

    const int tid  = threadIdx.x;
    const int tp   = blockIdx.x;            // tree pair 0..15
    const int b0   = blockIdx.y * BM;
    const int wave = tid >> 6;
    const int lane = tid & 63;
    const int quad = lane >> 4;
    const int lm   = lane & 15;
    const int wr   = wave >> 1;             // row half (64 rows)
    const int wc   = wave & 1;              // tree whose cols this wave computed

    if (tid < 128) {
        const int p = tid >> 6, node = tid & 63;
        bs2[p][node] = (node < N_NODES) ? bias[(tp * 2 + p) * N_NODES + node] : 0.f;
    }

    f32x4 acc[4][4];
#pragma unroll
    for (int m = 0; m < 4; ++m)
#pragma unroll
        for (int n = 0; n < 4; ++n)
            acc[m][n] = f32x4{0.f, 0.f, 0.f, 0.f};

    // ---- GEMM: C[128 x (2 trees x 64 nodes)] = xb . Wb^T, K=256, BK=64 ----
    for (int ko = 0; ko < F_DIM; ko += 64) {
        __syncthreads();
#pragma unroll
        for (int i = 0; i < 4; ++i) {
            const int r = wave * 32 + i * 8 + (lane >> 3);
            const int c = (lane & 7) ^ (r & 7);
            gl_lds16(&xb[(size_t)(b0 + r) * F_DIM + ko + c * 8],
                     &sm.g.A[(wave * 32 + i * 8) * 64]);
        }
#pragma unroll
        for (int i = 0; i < 4; ++i) {
            const int r = wave * 32 + i * 8 + (lane >> 3);
            const int c = (lane & 7) ^ (r & 7);
            gl_lds16(&Wb[(size_t)(tp * 128 + r) * F_DIM + ko + c * 8],
                     &sm.g.B[(wave * 32 + i * 8) * 64]);
        }
        __syncthreads();

#pragma unroll
        for (int ks = 0; ks < 2; ++ks) {
            bf16x8 af[4], bfr[4];
#pragma unroll
            for (int m = 0; m < 4; ++m) {
                const int r  = wr * 64 + m * 16 + lm;
                const int cp = (ks * 4 + quad) ^ (r & 7);
                af[m] = __builtin_bit_cast(bf16x8, *(ushort8_t*)&sm.g.A[r * 64 + cp * 8]);
            }
#pragma unroll
            for (int n = 0; n < 4; ++n) {
                const int r  = wc * 64 + n * 16 + lm;
                const int cp = (ks * 4 + quad) ^ (r & 7);
                bfr[n] = __builtin_bit_cast(bf16x8, *(ushort8_t*)&sm.g.B[r * 64 + cp * 8]);
            }
#pragma unroll
            for (int m = 0; m < 4; ++m)
#pragma unroll
                for (int n = 0; n < 4; ++n)
                    acc[m][n] = __builtin_amdgcn_mfma_f32_16x16x32_bf16(af[m], bfr[n], acc[m][n], 0, 0, 0);
        }
    }
    __syncthreads();   // GEMM LDS reads done; union becomes ss space

    // phi B-frags for both trees of the pair
    bf16x8 pb[2][2];
#pragma unroll
    for (int p = 0; p < 2; ++p)
#pragma unroll
        for (int k2 = 0; k2 < 2; ++k2)
            pb[p][k2] = __builtin_bit_cast(bf16x8,
                *(const ushort8_t*)&phiB[(size_t)(((tp * 2 + p) * 2 + k2) * 64 + lane) * 8]);

    // static walk-order h-split slot for nodes n*16+lm
    int slot[4];
#pragma unroll
    for (int n = 0; n < 4; ++n) {
        const int node = n * 16 + lm;
        const int np1  = node + 1;
        const int d    = 31 - __builtin_clz(np1);   // depth 0..5
        if (d == 0) slot[n] = 0;
        else {
            const int half = 1 << (d - 1);
            const int u    = np1 - (1 << d);
            const int hh   = (u >= half) ? 1 : 0;
            const int pos  = half + (u & (half - 1));
            slot[n] = hh * 32 + pos;
        }
    }

    // ---- sigmoid + scatter, ALL waves (wave's cols = tree wc); acc dies here ----
#pragma unroll
    for (int m = 0; m < 4; ++m)
#pragma unroll
        for (int n = 0; n < 4; ++n) {
            const int node = n * 16 + lm;
            const float bb = bs2[wc][node];
#pragma unroll
            for (int reg = 0; reg < 4; ++reg) {
                const int rr = wr * 64 + m * 16 + quad * 4 + reg;
                const float z = acc[m][n][reg] + bb;
                const float e = __expf(-z);
                const unsigned short sv = f2bf_hw(fast_rcp(1.0f + e));
                if (node < N_NODES) {
                    unsigned short* base = &sm.ss[(wc * BM + rr) * 64];
                    base[slot[n]] = sv;
                    if (node == 0) base[32] = sv;   // duplicate root to h=1 half
                }
            }
        }
    __syncthreads();   // the ONLY epilogue barrier

    const int row = tid >> 1;
    const int h   = tid & 1;
    const int rs  = row & 7;

    f32x4 accp[2] = { f32x4{0.f,0.f,0.f,0.f}, f32x4{0.f,0.f,0.f,0.f} };

    // Epilogue p-loop: barrier-free. Each wave touches only rows wave*32..+31,
    // and within a wave the in-order LDS pipe makes read-then-overwrite safe.
    for (int p = 0; p < 2; ++p) {
        unsigned short* ssp = &sm.ss[p * (BM * 64)];
        // walk: read this thread's 64 B (32 walk-order nodes) into registers
        unsigned int w[16];
        {
            const unsigned short* sp = &ssp[row * 64 + h * 32];
            *(uint4*)&w[0]  = *(const uint4*)&sp[0];
            *(uint4*)&w[4]  = *(const uint4*)&sp[8];
            *(uint4*)&w[8]  = *(const uint4*)&sp[16];
            *(uint4*)&w[12] = *(const uint4*)&sp[24];
        }
#define VAL(j) ((j) & 1 ? __uint_as_float(w[(j) >> 1] & 0xffff0000u) \
                        : __uint_as_float(w[(j) >> 1] << 16))
        const float s0 = VAL(0);
        const float q1 = h ? s0 : (1.0f - s0);
        float q2[2], q3[4], q4[8], q5[16];
        {
            const float tv = VAL(1);
            q2[1] = q1 * tv; q2[0] = q1 - q2[1];
        }
#pragma unroll
        for (int v = 0; v < 2; ++v) {
            const float tv = VAL(2 + v);
            q3[2 * v + 1] = q2[v] * tv; q3[2 * v] = q2[v] - q3[2 * v + 1];
        }
#pragma unroll
        for (int v = 0; v < 4; ++v) {
            const float tv = VAL(4 + v);
            q4[2 * v + 1] = q3[v] * tv; q4[2 * v] = q3[v] - q4[2 * v + 1];
        }
#pragma unroll
        for (int v = 0; v < 8; ++v) {
            const float tv = VAL(8 + v);
            q5[2 * v + 1] = q4[v] * tv; q5[2 * v] = q4[v] - q5[2 * v + 1];
        }
        // leaves (4 chunks of 8) -> lv overlaid IN-PLACE on ss[p] rows
#pragma unroll
        for (int i = 0; i < 4; ++i) {
            float q6[8];
#pragma unroll
            for (int v = 0; v < 4; ++v) {
                const float tv = VAL(16 + i * 4 + v);
                q6[2 * v + 1] = q5[i * 4 + v] * tv;
                q6[2 * v]     = q5[i * 4 + v] - q6[2 * v + 1];
            }
            uint4 wv;
            wv.x = pk2bf_hw(q6[0], q6[1]);
            wv.y = pk2bf_hw(q6[2], q6[3]);
            wv.z = pk2bf_hw(q6[4], q6[5]);
            wv.w = pk2bf_hw(q6[6], q6[7]);
            *(uint4*)&ssp[row * 64 + ((h * 4 + i) ^ rs) * 8] = wv;
        }
#undef VAL

        // phi contraction: wave-local rows wave*32..+31
#pragma unroll
        for (int mg = 0; mg < 2; ++mg)
#pragma unroll
            for (int k2 = 0; k2 < 2; ++k2) {
                const int r2 = wave * 32 + mg * 16 + lm;
                const int cp = (k2 * 4 + quad) ^ (r2 & 7);
                const bf16x8 afr = __builtin_bit_cast(bf16x8,
                    *(ushort8_t*)&ssp[r2 * 64 + cp * 8]);
                accp[mg] = __builtin_amdgcn_mfma_f32_16x16x32_bf16(afr, pb[p][k2], accp[mg], 0, 0, 0);
            }
    }

    // ---- commit: col=lm (0..7), row=quad*4+reg; accp sums both trees ----
    if (lm < P_DIM) {
#pragma unroll
        for (int mg = 0; mg < 2; ++mg)
#pragma unroll
            for (int reg = 0; reg < 4; ++reg) {
                const int r2 = wave * 32 + mg * 16 + quad * 4 + reg;
                atomicAdd(&out[(size_t)(b0 + r2) * P_DIM + lm], SHRINK * accp[mg][reg]);
            }
    }
}

extern "C" void kernel_launch(void* const* d_in, const int* in_sizes, int n_in,
                              void* d_out, int out_size, void* d_ws, size_t ws_size,
                              hipStream_t stream) {
    const float* x    = (const float*)d_in[0];
    const float* W    = (const float*)d_in[1];
    const float* bias = (const float*)d_in[2];
    const float* phi  = (const float*)d_in[3];
    float* out = (float*)d_out;

    unsigned short* xb   = (unsigned short*)d_ws;                    // 4 MB
    unsigned short* Wb   = xb + (size_t)B_TOT * F_DIM;               // 1 MB
    unsigned short* phiB = Wb + (size_t)T_TREES * 64 * F_DIM;        // 64 KB

    cvt_all<<<dim3(2640), dim3(256), 0, stream>>>(x, W, phi, xb, Wb, phiB, out);

    dim3 grid(T_TREES / 2, B_TOT / BM);
    softgbm_main<<<grid, dim3(256), 0, stream>>>(xb, Wb, phiB, bias, out);
}